// Round 12
// baseline (134.535 us; speedup 1.0000x reference)
//
#include <hip/hip_runtime.h>
#include <hip/hip_bf16.h>

// Problem constants (from reference setup_inputs)
#define T_TOK   32768
#define N_SLOTS 128
#define D_DIM   4096
#define B_DIM   4

// GEMM tiling: sums[128, 4096] = m^T[128, T] @ h[T, 4096]
#define NCHUNK  16                  // split-T
#define CTOK    (T_TOK / NCHUNK)    // 2048 tokens per block
#define KB      64                  // tokens per LDS tile (MFMA K per tile)
#define NT      (CTOK / KB)         // 32 tiles
#define WCOLS   256                 // D columns per block (1 KB per row-visit)
#define NSLICE  (D_DIM / WCOLS)     // 16
#define THREADS 512                 // 8 waves

typedef unsigned long long u64;
typedef __attribute__((ext_vector_type(8))) short short8;   // 8 bf16
typedef __attribute__((ext_vector_type(4))) float f32x4;

// ws layout: partial[NCHUNK][128][4096] bf16 (16 MiB), then counts
#define PARTIAL_BYTES ((size_t)NCHUNK * N_SLOTS * D_DIM * 2)
#define COUNTS_OFF    PARTIAL_BYTES

// Barrier with LDS-only drain (prefetched global loads stay in flight).
#define BAR_LGKM() do { \
    asm volatile("s_waitcnt lgkmcnt(0)" ::: "memory"); \
    __builtin_amdgcn_s_barrier(); \
  } while (0)

__device__ __forceinline__ unsigned int pack_bf2(float lo, float hi) {
  unsigned short a = __bfloat16_as_ushort(__float2bfloat16(lo));
  unsigned short b = __bfloat16_as_ushort(__float2bfloat16(hi));
  return (unsigned int)a | ((unsigned int)b << 16);
}
__device__ __forceinline__ unsigned short bf16u(float x) {
  return __bfloat16_as_ushort(__float2bfloat16(x));
}

// ---------------------------------------------------------------------------
// Kernel 1: counts[n] = number of tokens whose (deduped) top-K set contains n.
// ---------------------------------------------------------------------------
__global__ __launch_bounds__(256) void prep_kernel(const int* __restrict__ sidx,
                                                   int* __restrict__ counts) {
  __shared__ int cnt[N_SLOTS];
  const int tid = threadIdx.x;
  if (tid < N_SLOTS) cnt[tid] = 0;
  __syncthreads();

  const int t = blockIdx.x * 256 + tid;
  const int4 a = ((const int4*)sidx)[2 * t];
  const int4 b = ((const int4*)sidx)[2 * t + 1];
  int idx[8] = {a.x, a.y, a.z, a.w, b.x, b.y, b.z, b.w};

  #pragma unroll
  for (int k = 0; k < 8; ++k) {
    int n = idx[k];
    bool dup = false;
    #pragma unroll
    for (int j = 0; j < 8; ++j)
      if (j < k) dup |= (idx[j] == n);
    if (!dup && (unsigned)n < (unsigned)N_SLOTS) atomicAdd(&cnt[n], 1);
  }
  __syncthreads();
  if (tid < N_SLOTS && cnt[tid] > 0) atomicAdd(&counts[tid], cnt[tid]);
}

// ---------------------------------------------------------------------------
// Kernel 2: MFMA GEMM over the 512 MB h stream. R11 geometry (WCOLS=256,
// 512 threads, grid 256, LDS 96 KiB, 2-barrier tile loop, bf16 partials)
// + PREFETCH DISTANCE 2: two register sets ping-pong so ~128 KB/CU of
// global loads stay in flight (vs 64 KB at distance 1, which exactly
// matched the 19.5 GB/s/CU steady-state demand with zero slack).
// LDS layouts (bf16 elem index, XOR-swizzled; k-pairs packed in b32 words):
//   h tile: elem = col*64 + (k ^ ((col&7)<<3)), col 0..255  (32 KiB/buf)
//   m tile: elem = row*64 + (tok ^ ((row&7)<<3)), row 0..127 (16 KiB/buf)
// m built by zero + scatter of bf16 1.0 (dups benign -> dedup free).
// ---------------------------------------------------------------------------
__global__ __launch_bounds__(THREADS, 2) void sums_kernel(
    const float* __restrict__ hidden, const int* __restrict__ sidx,
    unsigned short* __restrict__ partial) {
  __shared__ unsigned int   h_w[2][WCOLS * 32];   // 32 KiB per buffer
  __shared__ unsigned short m_u[2][N_SLOTS * KB]; // 16 KiB per buffer

  const int tid = threadIdx.x;
  const int slice = blockIdx.x & (NSLICE - 1);
  const int chunk = blockIdx.x / NSLICE;
  const int d0 = slice * WCOLS;
  const int cb = chunk * CTOK;

  // staging coords: thread owns token-pair kp (k=2kp,2kp+1) x 16 cols
  const int kp = tid & 31;
  const int cg = tid >> 5;   // col group 0..15 (16 cols each)

  // scatter coords: thread tid owns flat entry j=tid (64 tok x 8 K = 512)
  const int tok0 = tid >> 3;

  // compute coords
  const int lane = tid & 63;
  const int wv   = tid >> 6;   // wave 0..7 -> col-tiles {2wv, 2wv+1}
  const int l15  = lane & 15;
  const int lk   = lane >> 4;  // k-group 0..3

  f32x4 acc[8][2];
  #pragma unroll
  for (int i = 0; i < 8; ++i)
    #pragma unroll
    for (int j = 0; j < 2; ++j)
      acc[i][j] = (f32x4){0.f, 0.f, 0.f, 0.f};

  // two prefetch register sets (distance-2 pipeline)
  float4 fa0[4], fb0[4]; int s0;   // set 0: tiles 0,2,4,...
  float4 fa1[4], fb1[4]; int s1;   // set 1: tiles 1,3,5,...

  const float* hbase = hidden + (size_t)(cb + 2 * kp) * D_DIM + d0 + cg * 16;
  const size_t tileStep = (size_t)KB * D_DIM;   // 64 tokens

  {  // prologue: issue loads for tiles 0 and 1
    #pragma unroll
    for (int q = 0; q < 4; ++q) {
      fa0[q] = ((const float4*)hbase)[q];
      fb0[q] = ((const float4*)(hbase + D_DIM))[q];
    }
    s0 = sidx[cb * 8 + tid];
    const float* hp1 = hbase + tileStep;
    #pragma unroll
    for (int q = 0; q < 4; ++q) {
      fa1[q] = ((const float4*)hp1)[q];
      fb1[q] = ((const float4*)(hp1 + D_DIM))[q];
    }
    s1 = sidx[(cb + KB) * 8 + tid];
  }

  #pragma unroll 2
  for (int t = 0; t < NT; ++t) {
    const int b = t & 1;
    // select the register set holding tile t (even->set0, odd->set1)
    float4* fa = (b == 0) ? fa0 : fa1;
    float4* fb = (b == 0) ? fb0 : fb1;
    const int cs0 = (b == 0) ? s0 : s1;

    // ---- stage h tile from regs: cvt f32->bf16, pack (k,k+1), b32 write ----
    #pragma unroll
    for (int q = 0; q < 4; ++q) {
      const int colbase = cg * 16 + q * 4;
      const float ax[4] = {fa[q].x, fa[q].y, fa[q].z, fa[q].w};
      const float bx[4] = {fb[q].x, fb[q].y, fb[q].z, fb[q].w};
      #pragma unroll
      for (int c = 0; c < 4; ++c) {
        const int col = colbase + c;
        h_w[b][col * 32 + (kp ^ ((col & 7) << 2))] = pack_bf2(ax[c], bx[c]);
      }
    }

    // ---- re-issue this register set with tile t+2's loads ----
    if (t + 2 < NT) {
      const float* hp = hbase + (size_t)(t + 2) * tileStep;
      #pragma unroll
      for (int q = 0; q < 4; ++q) {
        fa[q] = ((const float4*)hp)[q];
        fb[q] = ((const float4*)(hp + D_DIM))[q];
      }
      const int tb = cb + (t + 2) * KB;
      if (b == 0) s0 = sidx[tb * 8 + tid];
      else        s1 = sidx[tb * 8 + tid];
    }

    // ---- zero m tile: 16 KiB via 512 threads x 2 uint4 ----
    {
      uint4* mz = (uint4*)m_u[b];
      const uint4 z = make_uint4(0, 0, 0, 0);
      mz[tid] = z;
      mz[THREADS + tid] = z;
    }
    BAR_LGKM();   // zero visible before scatter (LDS only)

    // ---- scatter m: write bf16 1.0 at (slot, token) ----
    {
      const int n0 = cs0 & (N_SLOTS - 1);
      m_u[b][n0 * 64 + (tok0 ^ ((n0 & 7) << 3))] = 0x3F80;
    }
    BAR_LGKM();   // tile staged before compute (LDS only)

    // ---- MFMA: acc += m^T(tile) @ h(tile) ----
    {
      const unsigned short* mb = m_u[b];
      const unsigned short* hb = (const unsigned short*)h_w[b];
      #pragma unroll
      for (int ks = 0; ks < 2; ++ks) {
        const int kbase = ks * 32 + lk * 8;
        const int col0 = (wv * 2) * 16 + l15;
        const int col1 = (wv * 2 + 1) * 16 + l15;
        const short8 bf0 = *(const short8*)&hb[col0 * 64 + (kbase ^ ((col0 & 7) << 3))];
        const short8 bf1 = *(const short8*)&hb[col1 * 64 + (kbase ^ ((col1 & 7) << 3))];
        #pragma unroll
        for (int mt = 0; mt < 8; ++mt) {
          const int row = mt * 16 + l15;
          const short8 af = *(const short8*)&mb[row * 64 + (kbase ^ ((row & 7) << 3))];
          acc[mt][0] = __builtin_amdgcn_mfma_f32_16x16x32_bf16(af, bf0, acc[mt][0], 0, 0, 0);
          acc[mt][1] = __builtin_amdgcn_mfma_f32_16x16x32_bf16(af, bf1, acc[mt][1], 0, 0, 0);
        }
      }
    }
  }

  // ---- flush: bf16 stores of this block's 128x256 tile into partial[chunk].
  unsigned short* pbase = partial + (size_t)chunk * N_SLOTS * D_DIM;
  #pragma unroll
  for (int mt = 0; mt < 8; ++mt)
    #pragma unroll
    for (int j = 0; j < 2; ++j) {
      const int col = d0 + (wv * 2 + j) * 16 + l15;
      #pragma unroll
      for (int r = 0; r < 4; ++r) {
        const int row = mt * 16 + lk * 4 + r;
        pbase[(size_t)row * D_DIM + col] = bf16u(acc[mt][j][r]);
      }
    }
}

// ---------------------------------------------------------------------------
// Kernel 3: out = memory, with row batch_idx blended:
//   counts>0 ? 0.1*(sum_c partial[c])/counts + 0.9*cur : cur
// ---------------------------------------------------------------------------
__global__ __launch_bounds__(256) void final_kernel(const float* __restrict__ memory,
                                                    const unsigned short* __restrict__ partial,
                                                    const int* __restrict__ counts,
                                                    const int* __restrict__ bidx_p,
                                                    float* __restrict__ out) {
  const size_t i = (size_t)blockIdx.x * 256 + threadIdx.x;   // float4 index
  float4 v = ((const float4*)memory)[i];
  const size_t rowLen4 = (size_t)N_SLOTS * (D_DIM / 4);
  const size_t rowStart = (size_t)(*bidx_p) * rowLen4;
  if (i >= rowStart && i < rowStart + rowLen4) {
    const size_t rel = i - rowStart;
    const int n  = (int)(rel / (D_DIM / 4));
    const int d4 = (int)(rel % (D_DIM / 4));
    const int c = counts[n];
    if (c > 0) {
      float4 s = {0.f, 0.f, 0.f, 0.f};
      #pragma unroll
      for (int ch = 0; ch < NCHUNK; ++ch) {
        const ushort4 p = ((const ushort4*)partial)[((size_t)ch * N_SLOTS + n) * (D_DIM / 4) + d4];
        s.x += __uint_as_float((unsigned int)p.x << 16);
        s.y += __uint_as_float((unsigned int)p.y << 16);
        s.z += __uint_as_float((unsigned int)p.z << 16);
        s.w += __uint_as_float((unsigned int)p.w << 16);
      }
      const float w = 0.1f / (float)c;
      v.x = s.x * w + 0.9f * v.x;
      v.y = s.y * w + 0.9f * v.y;
      v.z = s.z * w + 0.9f * v.z;
      v.w = s.w * w + 0.9f * v.w;
    }
  }
  ((float4*)out)[i] = v;
}

extern "C" void kernel_launch(void* const* d_in, const int* in_sizes, int n_in,
                              void* d_out, int out_size, void* d_ws, size_t ws_size,
                              hipStream_t stream) {
  const float* memory = (const float*)d_in[0];
  const float* hidden = (const float*)d_in[1];
  const int*   sidx   = (const int*)d_in[2];
  const int*   bidx   = (const int*)d_in[3];
  float* out = (float*)d_out;

  char* ws = (char*)d_ws;
  unsigned short* partial = (unsigned short*)ws;
  int* counts = (int*)(ws + COUNTS_OFF);

  // zero counts only (partial is fully overwritten every call)
  hipMemsetAsync(counts, 0, 512, stream);

  prep_kernel<<<T_TOK / 256, 256, 0, stream>>>(sidx, counts);

  sums_kernel<<<NCHUNK * NSLICE, THREADS, 0, stream>>>(hidden, sidx, partial);

  const int totalVec4 = B_DIM * N_SLOTS * (D_DIM / 4);   // 524288
  final_kernel<<<totalVec4 / 256, 256, 0, stream>>>(memory, partial, counts, bidx, out);
}

// Round 13
// 117.482 us; speedup vs baseline: 1.1451x; 1.1451x over previous
//
#include <hip/hip_runtime.h>
#include <hip/hip_bf16.h>

// Problem constants (from reference setup_inputs)
#define T_TOK   32768
#define N_SLOTS 128
#define D_DIM   4096
#define B_DIM   4

// GEMM tiling: sums[128, 4096] = m^T[128, T] @ h[T, 4096]
#define NCHUNK  16                  // split-T
#define CTOK    (T_TOK / NCHUNK)    // 2048 tokens per block
#define KB      64                  // tokens per LDS tile (MFMA K per tile)
#define NT      (CTOK / KB)         // 32 tiles
#define WCOLS   256                 // D columns per block (1 KB per row-visit)
#define NSLICE  (D_DIM / WCOLS)     // 16
#define THREADS 512                 // 8 waves

typedef unsigned long long u64;
typedef __attribute__((ext_vector_type(8))) short short8;   // 8 bf16
typedef __attribute__((ext_vector_type(4))) float f32x4;

// ws layout: partial[NCHUNK][128][4096] bf16 (16 MiB), then counts
#define PARTIAL_BYTES ((size_t)NCHUNK * N_SLOTS * D_DIM * 2)
#define COUNTS_OFF    PARTIAL_BYTES

// Barrier with LDS-only drain (prefetched global loads stay in flight).
#define BAR_LGKM() do { \
    asm volatile("s_waitcnt lgkmcnt(0)" ::: "memory"); \
    __builtin_amdgcn_s_barrier(); \
  } while (0)

__device__ __forceinline__ unsigned int pack_bf2(float lo, float hi) {
  unsigned short a = __bfloat16_as_ushort(__float2bfloat16(lo));
  unsigned short b = __bfloat16_as_ushort(__float2bfloat16(hi));
  return (unsigned int)a | ((unsigned int)b << 16);
}
__device__ __forceinline__ unsigned short bf16u(float x) {
  return __bfloat16_as_ushort(__float2bfloat16(x));
}

// ---------------------------------------------------------------------------
// Kernel 1: counts[n] = number of tokens whose (deduped) top-K set contains n.
// ---------------------------------------------------------------------------
__global__ __launch_bounds__(256) void prep_kernel(const int* __restrict__ sidx,
                                                   int* __restrict__ counts) {
  __shared__ int cnt[N_SLOTS];
  const int tid = threadIdx.x;
  if (tid < N_SLOTS) cnt[tid] = 0;
  __syncthreads();

  const int t = blockIdx.x * 256 + tid;
  const int4 a = ((const int4*)sidx)[2 * t];
  const int4 b = ((const int4*)sidx)[2 * t + 1];
  int idx[8] = {a.x, a.y, a.z, a.w, b.x, b.y, b.z, b.w};

  #pragma unroll
  for (int k = 0; k < 8; ++k) {
    int n = idx[k];
    bool dup = false;
    #pragma unroll
    for (int j = 0; j < 8; ++j)
      if (j < k) dup |= (idx[j] == n);
    if (!dup && (unsigned)n < (unsigned)N_SLOTS) atomicAdd(&cnt[n], 1);
  }
  __syncthreads();
  if (tid < N_SLOTS && cnt[tid] > 0) atomicAdd(&counts[tid], cnt[tid]);
}

// ---------------------------------------------------------------------------
// Kernel 2: MFMA GEMM over the 512 MB h stream. R11 geometry: WCOLS=256,
// 512 threads, grid 256 (1 block/CU), LDS 96 KiB, 2-barrier tile loop,
// prefetch distance 1 (R10/R12 showed VGPRs allow exactly one set),
// bf16 partials (halves the partial roundtrip; added error ~1e-4).
// LDS layouts (bf16 elem index, XOR-swizzled; k-pairs packed in b32 words):
//   h tile: elem = col*64 + (k ^ ((col&7)<<3)), col 0..255  (32 KiB/buf)
//   m tile: elem = row*64 + (tok ^ ((row&7)<<3)), row 0..127 (16 KiB/buf)
// m built by zero + scatter of bf16 1.0 (dups benign -> dedup free);
// exactly ONE slot-entry per thread per tile (512 = 64 tok x 8 K).
// ---------------------------------------------------------------------------
__global__ __launch_bounds__(THREADS, 2) void sums_kernel(
    const float* __restrict__ hidden, const int* __restrict__ sidx,
    unsigned short* __restrict__ partial) {
  __shared__ unsigned int   h_w[2][WCOLS * 32];   // 32 KiB per buffer
  __shared__ unsigned short m_u[2][N_SLOTS * KB]; // 16 KiB per buffer

  const int tid = threadIdx.x;
  const int slice = blockIdx.x & (NSLICE - 1);
  const int chunk = blockIdx.x / NSLICE;
  const int d0 = slice * WCOLS;
  const int cb = chunk * CTOK;

  // staging coords: thread owns token-pair kp (k=2kp,2kp+1) x 16 cols
  const int kp = tid & 31;
  const int cg = tid >> 5;   // col group 0..15 (16 cols each)

  // scatter coords: thread tid owns flat entry j=tid (64 tok x 8 K = 512)
  const int tok0 = tid >> 3;

  // compute coords
  const int lane = tid & 63;
  const int wv   = tid >> 6;   // wave 0..7 -> col-tiles {2wv, 2wv+1}
  const int l15  = lane & 15;
  const int lk   = lane >> 4;  // k-group 0..3

  f32x4 acc[8][2];
  #pragma unroll
  for (int i = 0; i < 8; ++i)
    #pragma unroll
    for (int j = 0; j < 2; ++j)
      acc[i][j] = (f32x4){0.f, 0.f, 0.f, 0.f};

  float4 fa[4], fb[4];   // prefetched h: token 2kp and 2kp+1, 16 cols each
  int s0;                // prefetched slot index (flat j = tid of this tile)

  {  // prologue: loads for tile 0
    const float* hp = hidden + (size_t)(cb + 2 * kp) * D_DIM + d0 + cg * 16;
    #pragma unroll
    for (int q = 0; q < 4; ++q) {
      fa[q] = ((const float4*)hp)[q];
      fb[q] = ((const float4*)(hp + D_DIM))[q];
    }
    s0 = sidx[cb * 8 + tid];
  }

  for (int t = 0; t < NT; ++t) {
    const int b = t & 1;
    const int cs0 = s0;   // consume prefetched index this tile

    // ---- stage h tile: cvt f32->bf16, pack (k,k+1), b32 write (2-way free) --
    #pragma unroll
    for (int q = 0; q < 4; ++q) {
      const int colbase = cg * 16 + q * 4;
      const float ax[4] = {fa[q].x, fa[q].y, fa[q].z, fa[q].w};
      const float bx[4] = {fb[q].x, fb[q].y, fb[q].z, fb[q].w};
      #pragma unroll
      for (int c = 0; c < 4; ++c) {
        const int col = colbase + c;
        h_w[b][col * 32 + (kp ^ ((col & 7) << 2))] = pack_bf2(ax[c], bx[c]);
      }
    }

    // ---- issue next tile's global loads (stay in flight across barriers) ----
    if (t + 1 < NT) {
      const int tb = cb + (t + 1) * KB;
      const float* hp = hidden + (size_t)(tb + 2 * kp) * D_DIM + d0 + cg * 16;
      #pragma unroll
      for (int q = 0; q < 4; ++q) {
        fa[q] = ((const float4*)hp)[q];
        fb[q] = ((const float4*)(hp + D_DIM))[q];
      }
      s0 = sidx[tb * 8 + tid];
    }

    // ---- zero m tile: 16 KiB via 512 threads x 2 uint4 ----
    {
      uint4* mz = (uint4*)m_u[b];
      const uint4 z = make_uint4(0, 0, 0, 0);
      mz[tid] = z;
      mz[THREADS + tid] = z;
    }
    BAR_LGKM();   // zero visible before scatter (LDS only)

    // ---- scatter m: write bf16 1.0 at (slot, token) ----
    {
      const int n0 = cs0 & (N_SLOTS - 1);
      m_u[b][n0 * 64 + (tok0 ^ ((n0 & 7) << 3))] = 0x3F80;
    }
    BAR_LGKM();   // tile staged before compute (LDS only)

    // ---- MFMA: acc += m^T(tile) @ h(tile) ----
    {
      const unsigned short* mb = m_u[b];
      const unsigned short* hb = (const unsigned short*)h_w[b];
      #pragma unroll
      for (int ks = 0; ks < 2; ++ks) {
        const int kbase = ks * 32 + lk * 8;
        const int col0 = (wv * 2) * 16 + l15;
        const int col1 = (wv * 2 + 1) * 16 + l15;
        const short8 bf0 = *(const short8*)&hb[col0 * 64 + (kbase ^ ((col0 & 7) << 3))];
        const short8 bf1 = *(const short8*)&hb[col1 * 64 + (kbase ^ ((col1 & 7) << 3))];
        #pragma unroll
        for (int mt = 0; mt < 8; ++mt) {
          const int row = mt * 16 + l15;
          const short8 af = *(const short8*)&mb[row * 64 + (kbase ^ ((row & 7) << 3))];
          acc[mt][0] = __builtin_amdgcn_mfma_f32_16x16x32_bf16(af, bf0, acc[mt][0], 0, 0, 0);
          acc[mt][1] = __builtin_amdgcn_mfma_f32_16x16x32_bf16(af, bf1, acc[mt][1], 0, 0, 0);
        }
      }
    }
  }

  // ---- flush: bf16 stores of this block's 128x256 tile into partial[chunk].
  unsigned short* pbase = partial + (size_t)chunk * N_SLOTS * D_DIM;
  #pragma unroll
  for (int mt = 0; mt < 8; ++mt)
    #pragma unroll
    for (int j = 0; j < 2; ++j) {
      const int col = d0 + (wv * 2 + j) * 16 + l15;
      #pragma unroll
      for (int r = 0; r < 4; ++r) {
        const int row = mt * 16 + lk * 4 + r;
        pbase[(size_t)row * D_DIM + col] = bf16u(acc[mt][j][r]);
      }
    }
}

// ---------------------------------------------------------------------------
// Kernel 3: out = memory, with row batch_idx blended:
//   counts>0 ? 0.1*(sum_c partial[c])/counts + 0.9*cur : cur
// ---------------------------------------------------------------------------
__global__ __launch_bounds__(256) void final_kernel(const float* __restrict__ memory,
                                                    const unsigned short* __restrict__ partial,
                                                    const int* __restrict__ counts,
                                                    const int* __restrict__ bidx_p,
                                                    float* __restrict__ out) {
  const size_t i = (size_t)blockIdx.x * 256 + threadIdx.x;   // float4 index
  float4 v = ((const float4*)memory)[i];
  const size_t rowLen4 = (size_t)N_SLOTS * (D_DIM / 4);
  const size_t rowStart = (size_t)(*bidx_p) * rowLen4;
  if (i >= rowStart && i < rowStart + rowLen4) {
    const size_t rel = i - rowStart;
    const int n  = (int)(rel / (D_DIM / 4));
    const int d4 = (int)(rel % (D_DIM / 4));
    const int c = counts[n];
    if (c > 0) {
      float4 s = {0.f, 0.f, 0.f, 0.f};
      #pragma unroll
      for (int ch = 0; ch < NCHUNK; ++ch) {
        const ushort4 p = ((const ushort4*)partial)[((size_t)ch * N_SLOTS + n) * (D_DIM / 4) + d4];
        s.x += __uint_as_float((unsigned int)p.x << 16);
        s.y += __uint_as_float((unsigned int)p.y << 16);
        s.z += __uint_as_float((unsigned int)p.z << 16);
        s.w += __uint_as_float((unsigned int)p.w << 16);
      }
      const float w = 0.1f / (float)c;
      v.x = s.x * w + 0.9f * v.x;
      v.y = s.y * w + 0.9f * v.y;
      v.z = s.z * w + 0.9f * v.z;
      v.w = s.w * w + 0.9f * v.w;
    }
  }
  ((float4*)out)[i] = v;
}

extern "C" void kernel_launch(void* const* d_in, const int* in_sizes, int n_in,
                              void* d_out, int out_size, void* d_ws, size_t ws_size,
                              hipStream_t stream) {
  const float* memory = (const float*)d_in[0];
  const float* hidden = (const float*)d_in[1];
  const int*   sidx   = (const int*)d_in[2];
  const int*   bidx   = (const int*)d_in[3];
  float* out = (float*)d_out;

  char* ws = (char*)d_ws;
  unsigned short* partial = (unsigned short*)ws;
  int* counts = (int*)(ws + COUNTS_OFF);

  // zero counts only (partial is fully overwritten every call)
  hipMemsetAsync(counts, 0, 512, stream);

  prep_kernel<<<T_TOK / 256, 256, 0, stream>>>(sidx, counts);

  sums_kernel<<<NCHUNK * NSLICE, THREADS, 0, stream>>>(hidden, sidx, partial);

  const int totalVec4 = B_DIM * N_SLOTS * (D_DIM / 4);   // 524288
  final_kernel<<<totalVec4 / 256, 256, 0, stream>>>(memory, partial, counts, bidx, out);
}